// Round 1
// baseline (144.917 us; speedup 1.0000x reference)
//
#include <hip/hip_runtime.h>
#include <stdint.h>

// Problem: out[m,e,k] = sum_n A[m,n] * W[e,n,k]
// == GEMM C[8192,2048] = A[8192,1024] x B[1024,2048], B[n, e*32+k] = W[e,n,k]
// Output flat layout m*2048 + e*32 + k matches [M,E,K] exactly.

#define M_DIM 8192
#define N_IN  1024   // reduction dim
#define E_DIM 64
#define K_DIM 32
#define J_DIM 2048   // E*K output columns

typedef __attribute__((ext_vector_type(8))) __bf16 bf16x8;
typedef __attribute__((ext_vector_type(4))) float floatx4;

__device__ inline unsigned short f2bf(float f) {
    union { float f; unsigned u; } v; v.f = f;
    unsigned u = v.u;
    u += 0x7fff + ((u >> 16) & 1);   // round-to-nearest-even
    return (unsigned short)(u >> 16);
}

// A [8192,1024] f32 -> Ab bf16 (same layout). 4 elements/thread.
__global__ __launch_bounds__(256) void convert_A(const float* __restrict__ A,
                                                 unsigned short* __restrict__ Ab) {
    size_t i = (size_t)blockIdx.x * 256 + threadIdx.x;
    const float4 v = ((const float4*)A)[i];
    ushort4 o;
    o.x = f2bf(v.x); o.y = f2bf(v.y); o.z = f2bf(v.z); o.w = f2bf(v.w);
    ((ushort4*)Ab)[i] = o;
}

// W [64][1024][32] f32 -> Bt [2048][1024] bf16 with Bt[e*32+k][n] = W[e][n][k].
// Per block: one expert e, one 64-row slab n0..n0+64. LDS transpose, coalesced both ways.
__global__ __launch_bounds__(256) void convert_W(const float* __restrict__ W,
                                                 unsigned short* __restrict__ Bt) {
    __shared__ unsigned short lds[32 * 65];   // [k][r], pad 65 to break conflicts
    const int t  = threadIdx.x;
    const int e  = blockIdx.y;
    const int n0 = blockIdx.x * 64;
    const float* Wb = W + ((size_t)e * N_IN + n0) * K_DIM;
#pragma unroll
    for (int i = 0; i < 8; ++i) {
        int idx = i * 256 + t;            // 0..2047 over [r=64][k=32]
        int r = idx >> 5, k = idx & 31;
        lds[k * 65 + r] = f2bf(Wb[idx]);  // Wb[r*32+k] == Wb[idx], coalesced read
    }
    __syncthreads();
    unsigned* out = (unsigned*)(Bt + (size_t)e * K_DIM * N_IN + n0);
#pragma unroll
    for (int i = 0; i < 4; ++i) {
        int idx = i * 256 + t;            // 0..1023 over [k=32][p=32] (p = n-pair)
        int k = idx >> 5, p = idx & 31;
        unsigned lo = lds[k * 65 + 2 * p];
        unsigned hi = lds[k * 65 + 2 * p + 1];
        out[(size_t)k * (N_IN / 2) + p] = lo | (hi << 16);  // coalesced write
    }
}

// m97-style bf16 GEMM, B^T input. 128x128 tile, BK=64, 256 threads (4 waves 2x2),
// each wave: 4x4 grid of 16x16x32 MFMAs. global_load_lds width=16 staging.
__global__ __launch_bounds__(256) void gemm_bt(const unsigned short* __restrict__ Ab,
                                               const unsigned short* __restrict__ Bb,
                                               float* __restrict__ C) {
    __shared__ unsigned short As[128 * 64];   // 16 KB, row-major [m][k], unpadded
    __shared__ unsigned short Bs[128 * 64];   // 16 KB, row-major [j][k]

    const int tid  = threadIdx.x;
    const int wave = tid >> 6;
    const int lane = tid & 63;
    const int wm = wave >> 1, wn = wave & 1;
    const int m0 = blockIdx.x * 128;
    const int j0 = blockIdx.y * 128;

    floatx4 acc[4][4];
#pragma unroll
    for (int i = 0; i < 4; ++i)
#pragma unroll
        for (int j = 0; j < 4; ++j) acc[i][j] = (floatx4)(0.0f);

    // Staging: tile is 128 rows x 64 cols bf16 = 16 KB = 16 chunks of 1 KB.
    // One global_load_lds inst per wave stages 1 chunk (64 lanes x 16 B).
    // Lane covers tile bytes chunk*1024 + lane*16 -> row = chunk*8 + lane/8,
    // col = (lane&7)*8 elements. LDS dest = base + chunk*1024 (wave-uniform).
    const int lrow8 = lane >> 3;
    const int lcol  = (lane & 7) * 8;

    for (int kb = 0; kb < N_IN; kb += 64) {
#pragma unroll
        for (int l = 0; l < 4; ++l) {
            const int chunk = l * 4 + wave;          // 0..15
            const int row   = chunk * 8 + lrow8;     // 0..127
            const unsigned short* ga = Ab + (size_t)(m0 + row) * N_IN + kb + lcol;
            __builtin_amdgcn_global_load_lds(
                (const __attribute__((address_space(1))) unsigned int*)ga,
                (__attribute__((address_space(3))) unsigned int*)(As + chunk * 512),
                16, 0, 0);
            const unsigned short* gb = Bb + (size_t)(j0 + row) * N_IN + kb + lcol;
            __builtin_amdgcn_global_load_lds(
                (const __attribute__((address_space(1))) unsigned int*)gb,
                (__attribute__((address_space(3))) unsigned int*)(Bs + chunk * 512),
                16, 0, 0);
        }
        __syncthreads();

#pragma unroll
        for (int kk = 0; kk < 64; kk += 32) {
            bf16x8 af[4], bfr[4];
            const int colk = kk + (lane >> 4) * 8;   // A/B frag: k = quad*8 + j
#pragma unroll
            for (int i = 0; i < 4; ++i)
                af[i] = *(const bf16x8*)(As + (wm * 64 + i * 16 + (lane & 15)) * 64 + colk);
#pragma unroll
            for (int j = 0; j < 4; ++j)
                bfr[j] = *(const bf16x8*)(Bs + (wn * 64 + j * 16 + (lane & 15)) * 64 + colk);
#pragma unroll
            for (int i = 0; i < 4; ++i)
#pragma unroll
                for (int j = 0; j < 4; ++j)
                    acc[i][j] = __builtin_amdgcn_mfma_f32_16x16x32_bf16(
                        af[i], bfr[j], acc[i][j], 0, 0, 0);
        }
        __syncthreads();
    }

    // Epilogue: C/D layout col = lane&15, row = (lane>>4)*4 + reg
    const int crow = (lane >> 4) * 4;
    const int ccol = lane & 15;
#pragma unroll
    for (int i = 0; i < 4; ++i) {
#pragma unroll
        for (int j = 0; j < 4; ++j) {
            float* Cp = C + (size_t)(m0 + wm * 64 + i * 16 + crow) * J_DIM
                          + (j0 + wn * 64 + j * 16 + ccol);
#pragma unroll
            for (int r = 0; r < 4; ++r)
                Cp[(size_t)r * J_DIM] = acc[i][j][r];
        }
    }
}

extern "C" void kernel_launch(void* const* d_in, const int* in_sizes, int n_in,
                              void* d_out, int out_size, void* d_ws, size_t ws_size,
                              hipStream_t stream) {
    const float* A = (const float*)d_in[0];   // [8192,1024]
    const float* W = (const float*)d_in[1];   // [64,1024,32]
    float* out = (float*)d_out;               // [8192,64,32] == [8192,2048]

    unsigned short* Ab = (unsigned short*)d_ws;                 // 16 MB
    unsigned short* Bt = Ab + (size_t)M_DIM * N_IN;             // +4 MB

    convert_A<<<M_DIM * N_IN / (256 * 4), 256, 0, stream>>>(A, Ab);
    convert_W<<<dim3(N_IN / 64, E_DIM), 256, 0, stream>>>(W, Bt);
    gemm_bt<<<dim3(M_DIM / 128, J_DIM / 128), 256, 0, stream>>>(Ab, Bt, out);
}

// Round 2
// 138.266 us; speedup vs baseline: 1.0481x; 1.0481x over previous
//
#include <hip/hip_runtime.h>
#include <stdint.h>

// Problem: out[m,e,k] = sum_n A[m,n] * W[e,n,k]
// == GEMM C[8192,2048] = A[8192,1024] x B[1024,2048], B[n, e*32+k] = W[e,n,k]
// Output flat layout m*2048 + e*32 + k matches [M,E,K] exactly.

#define M_DIM 8192
#define N_IN  1024   // reduction dim
#define E_DIM 64
#define K_DIM 32
#define J_DIM 2048   // E*K output columns

typedef __attribute__((ext_vector_type(8))) __bf16 bf16x8;
typedef __attribute__((ext_vector_type(4))) float floatx4;

__device__ inline unsigned short f2bf(float f) {
    union { float f; unsigned u; } v; v.f = f;
    unsigned u = v.u;
    u += 0x7fff + ((u >> 16) & 1);   // round-to-nearest-even
    return (unsigned short)(u >> 16);
}

// A [8192,1024] f32 -> Ab bf16 (same layout). 4 elements/thread.
__global__ __launch_bounds__(256) void convert_A(const float* __restrict__ A,
                                                 unsigned short* __restrict__ Ab) {
    size_t i = (size_t)blockIdx.x * 256 + threadIdx.x;
    const float4 v = ((const float4*)A)[i];
    ushort4 o;
    o.x = f2bf(v.x); o.y = f2bf(v.y); o.z = f2bf(v.z); o.w = f2bf(v.w);
    ((ushort4*)Ab)[i] = o;
}

// W [64][1024][32] f32 -> Bt [2048][1024] bf16 with Bt[e*32+k][n] = W[e][n][k].
// Per block: one expert e, one 64-row slab n0..n0+64. LDS transpose, coalesced both ways.
__global__ __launch_bounds__(256) void convert_W(const float* __restrict__ W,
                                                 unsigned short* __restrict__ Bt) {
    __shared__ unsigned short lds[32 * 65];   // [k][r], pad 65 to break conflicts
    const int t  = threadIdx.x;
    const int e  = blockIdx.y;
    const int n0 = blockIdx.x * 64;
    const float* Wb = W + ((size_t)e * N_IN + n0) * K_DIM;
#pragma unroll
    for (int i = 0; i < 8; ++i) {
        int idx = i * 256 + t;            // 0..2047 over [r=64][k=32]
        int r = idx >> 5, k = idx & 31;
        lds[k * 65 + r] = f2bf(Wb[idx]);  // Wb[r*32+k] == Wb[idx], coalesced read
    }
    __syncthreads();
    unsigned* out = (unsigned*)(Bt + (size_t)e * K_DIM * N_IN + n0);
#pragma unroll
    for (int i = 0; i < 4; ++i) {
        int idx = i * 256 + t;            // 0..1023 over [k=32][p=32] (p = n-pair)
        int k = idx >> 5, p = idx & 31;
        unsigned lo = lds[k * 65 + 2 * p];
        unsigned hi = lds[k * 65 + 2 * p + 1];
        out[(size_t)k * (N_IN / 2) + p] = lo | (hi << 16);  // coalesced write
    }
}

// m97-style bf16 GEMM, B^T input. 128x128 tile, BK=64, 256 threads (4 waves 2x2),
// each wave: 4x4 grid of 16x16x32 MFMAs. global_load_lds width=16 staging.
//
// LDS XOR swizzle: each tile row is 8 groups of 16B; group g of row r is stored
// at slot g^(r&7). Kills the structural 16-way bank conflict of the 128B row
// stride (each quad's 16 lanes previously hit the same 4 banks). Staging lanes
// fetch the swizzled global group so the global_load_lds DMA (lane-contiguous
// LDS dest, no padding allowed) lands data in swizzled position.
__global__ __launch_bounds__(256) void gemm_bt(const unsigned short* __restrict__ Ab,
                                               const unsigned short* __restrict__ Bb,
                                               float* __restrict__ C) {
    __shared__ unsigned short As[128 * 64];   // 16 KB, [row][slot-group]
    __shared__ unsigned short Bs[128 * 64];   // 16 KB

    const int tid  = threadIdx.x;
    const int wave = tid >> 6;
    const int lane = tid & 63;
    const int wm = wave >> 1, wn = wave & 1;
    const int m0 = blockIdx.x * 128;
    const int j0 = blockIdx.y * 128;

    floatx4 acc[4][4];
#pragma unroll
    for (int i = 0; i < 4; ++i)
#pragma unroll
        for (int j = 0; j < 4; ++j) acc[i][j] = (floatx4)(0.0f);

    // Staging: 16 chunks of 1KB per tile; chunk = 8 rows x 64 cols.
    // Lane l covers LDS slot (row_in_chunk = l>>3, group = l&7); with the XOR
    // swizzle it must fetch global data group (l&7)^(l>>3) of that row.
    const int lrow8 = lane >> 3;
    const int gcol  = ((lane & 7) ^ lrow8) * 8;   // swizzled global column (elems)

    for (int kb = 0; kb < N_IN; kb += 64) {
#pragma unroll
        for (int l = 0; l < 4; ++l) {
            const int chunk = l * 4 + wave;          // 0..15
            const int row   = chunk * 8 + lrow8;     // 0..127
            const unsigned short* ga = Ab + (size_t)(m0 + row) * N_IN + kb + gcol;
            __builtin_amdgcn_global_load_lds(
                (const __attribute__((address_space(1))) unsigned int*)ga,
                (__attribute__((address_space(3))) unsigned int*)(As + chunk * 512),
                16, 0, 0);
            const unsigned short* gb = Bb + (size_t)(j0 + row) * N_IN + kb + gcol;
            __builtin_amdgcn_global_load_lds(
                (const __attribute__((address_space(1))) unsigned int*)gb,
                (__attribute__((address_space(3))) unsigned int*)(Bs + chunk * 512),
                16, 0, 0);
        }
        __syncthreads();

        const int l15  = lane & 15;
        const int quad = lane >> 4;
        const int l7   = lane & 7;
#pragma unroll
        for (int kk = 0; kk < 64; kk += 32) {
            bf16x8 af[4], bfr[4];
            // fragment k-group for this quad, swizzled by row&7 (== lane&7)
            const int sg = (((kk >> 3) + quad) ^ l7) * 8;
#pragma unroll
            for (int i = 0; i < 4; ++i)
                af[i] = *(const bf16x8*)(As + (wm * 64 + i * 16 + l15) * 64 + sg);
#pragma unroll
            for (int j = 0; j < 4; ++j)
                bfr[j] = *(const bf16x8*)(Bs + (wn * 64 + j * 16 + l15) * 64 + sg);
#pragma unroll
            for (int i = 0; i < 4; ++i)
#pragma unroll
                for (int j = 0; j < 4; ++j)
                    acc[i][j] = __builtin_amdgcn_mfma_f32_16x16x32_bf16(
                        af[i], bfr[j], acc[i][j], 0, 0, 0);
        }
        __syncthreads();
    }

    // Epilogue: C/D layout col = lane&15, row = (lane>>4)*4 + reg
    const int crow = (lane >> 4) * 4;
    const int ccol = lane & 15;
#pragma unroll
    for (int i = 0; i < 4; ++i) {
#pragma unroll
        for (int j = 0; j < 4; ++j) {
            float* Cp = C + (size_t)(m0 + wm * 64 + i * 16 + crow) * J_DIM
                          + (j0 + wn * 64 + j * 16 + ccol);
#pragma unroll
            for (int r = 0; r < 4; ++r)
                Cp[(size_t)r * J_DIM] = acc[i][j][r];
        }
    }
}

extern "C" void kernel_launch(void* const* d_in, const int* in_sizes, int n_in,
                              void* d_out, int out_size, void* d_ws, size_t ws_size,
                              hipStream_t stream) {
    const float* A = (const float*)d_in[0];   // [8192,1024]
    const float* W = (const float*)d_in[1];   // [64,1024,32]
    float* out = (float*)d_out;               // [8192,64,32] == [8192,2048]

    unsigned short* Ab = (unsigned short*)d_ws;                 // 16 MB
    unsigned short* Bt = Ab + (size_t)M_DIM * N_IN;             // +4 MB

    convert_A<<<M_DIM * N_IN / (256 * 4), 256, 0, stream>>>(A, Ab);
    convert_W<<<dim3(N_IN / 64, E_DIM), 256, 0, stream>>>(W, Bt);
    gemm_bt<<<dim3(M_DIM / 128, J_DIM / 128), 256, 0, stream>>>(Ab, Bt, out);
}

// Round 3
// 135.530 us; speedup vs baseline: 1.0693x; 1.0202x over previous
//
#include <hip/hip_runtime.h>
#include <stdint.h>

// Problem: out[m,e,k] = sum_n A[m,n] * W[e,n,k]
// == GEMM C[8192,2048] = A[8192,1024] x B[1024,2048], B[n, e*32+k] = W[e,n,k]
// Output flat layout m*2048 + e*32 + k matches [M,E,K] exactly.

#define M_DIM 8192
#define N_IN  1024   // reduction dim
#define E_DIM 64
#define K_DIM 32
#define J_DIM 2048   // E*K output columns

typedef __attribute__((ext_vector_type(8)))  __bf16 bf16x8;
typedef __attribute__((ext_vector_type(16))) float  floatx16;

__device__ inline unsigned short f2bf(float f) {
    union { float f; unsigned u; } v; v.f = f;
    unsigned u = v.u;
    u += 0x7fff + ((u >> 16) & 1);   // round-to-nearest-even
    return (unsigned short)(u >> 16);
}

// A [8192,1024] f32 -> Ab bf16 (same layout). 4 elements/thread.
__global__ __launch_bounds__(256) void convert_A(const float* __restrict__ A,
                                                 unsigned short* __restrict__ Ab) {
    size_t i = (size_t)blockIdx.x * 256 + threadIdx.x;
    const float4 v = ((const float4*)A)[i];
    ushort4 o;
    o.x = f2bf(v.x); o.y = f2bf(v.y); o.z = f2bf(v.z); o.w = f2bf(v.w);
    ((ushort4*)Ab)[i] = o;
}

// W [64][1024][32] f32 -> Bt [2048][1024] bf16 with Bt[e*32+k][n] = W[e][n][k].
// Per block: one expert e, one 64-row slab n0..n0+64. LDS transpose, coalesced both ways.
__global__ __launch_bounds__(256) void convert_W(const float* __restrict__ W,
                                                 unsigned short* __restrict__ Bt) {
    __shared__ unsigned short lds[32 * 65];   // [k][r], pad 65 to break conflicts
    const int t  = threadIdx.x;
    const int e  = blockIdx.y;
    const int n0 = blockIdx.x * 64;
    const float* Wb = W + ((size_t)e * N_IN + n0) * K_DIM;
#pragma unroll
    for (int i = 0; i < 8; ++i) {
        int idx = i * 256 + t;            // 0..2047 over [r=64][k=32]
        int r = idx >> 5, k = idx & 31;
        lds[k * 65 + r] = f2bf(Wb[idx]);  // Wb[r*32+k] == Wb[idx], coalesced read
    }
    __syncthreads();
    unsigned* out = (unsigned*)(Bt + (size_t)e * K_DIM * N_IN + n0);
#pragma unroll
    for (int i = 0; i < 4; ++i) {
        int idx = i * 256 + t;            // 0..1023 over [k=32][p=32] (p = n-pair)
        int k = idx >> 5, p = idx & 31;
        unsigned lo = lds[k * 65 + 2 * p];
        unsigned hi = lds[k * 65 + 2 * p + 1];
        out[(size_t)k * (N_IN / 2) + p] = lo | (hi << 16);  // coalesced write
    }
}

// bf16 GEMM, B^T input. 128x128 tile, BK=64, 256 threads (4 waves 2x2),
// each wave: 2x2 grid of 32x32x16 MFMAs (64x64 per wave).
// global_load_lds width=16 staging with XOR-swizzled LDS slots (conflict-free,
// verified round 2: SQ_LDS_BANK_CONFLICT == 0).
__global__ __launch_bounds__(256) void gemm_bt(const unsigned short* __restrict__ Ab,
                                               const unsigned short* __restrict__ Bb,
                                               float* __restrict__ C) {
    __shared__ unsigned short As[128 * 64];   // 16 KB, [row][slot-group]
    __shared__ unsigned short Bs[128 * 64];   // 16 KB

    const int tid  = threadIdx.x;
    const int wave = tid >> 6;
    const int lane = tid & 63;
    const int wm = wave >> 1, wn = wave & 1;
    const int m0 = blockIdx.x * 128;
    const int j0 = blockIdx.y * 128;

    floatx16 acc[2][2];
#pragma unroll
    for (int i = 0; i < 2; ++i)
#pragma unroll
        for (int j = 0; j < 2; ++j) acc[i][j] = (floatx16)(0.0f);

    // Staging: 16 chunks of 1KB per tile; chunk = 8 rows x 64 cols.
    // Lane l covers LDS slot (row_in_chunk = l>>3, group = l&7); with the XOR
    // swizzle it must fetch global data group (l&7)^(l>>3) of that row.
    const int lrow8 = lane >> 3;
    const int gcol  = ((lane & 7) ^ lrow8) * 8;   // swizzled global column (elems)

    for (int kb = 0; kb < N_IN; kb += 64) {
#pragma unroll
        for (int l = 0; l < 4; ++l) {
            const int chunk = l * 4 + wave;          // 0..15
            const int row   = chunk * 8 + lrow8;     // 0..127
            const unsigned short* ga = Ab + (size_t)(m0 + row) * N_IN + kb + gcol;
            __builtin_amdgcn_global_load_lds(
                (const __attribute__((address_space(1))) unsigned int*)ga,
                (__attribute__((address_space(3))) unsigned int*)(As + chunk * 512),
                16, 0, 0);
            const unsigned short* gb = Bb + (size_t)(j0 + row) * N_IN + kb + gcol;
            __builtin_amdgcn_global_load_lds(
                (const __attribute__((address_space(1))) unsigned int*)gb,
                (__attribute__((address_space(3))) unsigned int*)(Bs + chunk * 512),
                16, 0, 0);
        }
        __syncthreads();

        const int l31 = lane & 31;
        const int h   = lane >> 5;     // k-half selector for 32x32x16 A/B frags
        const int l7  = lane & 7;
#pragma unroll
        for (int kk = 0; kk < 64; kk += 16) {
            bf16x8 af[2], bfr[2];
            // A-frag: row = base + (lane&31), k = kk + h*8 + j (8 contiguous bf16)
            // swizzled slot group: ((kk>>3) + h) ^ (row&7), row&7 == lane&7
            const int sg = ((((kk >> 3) + h) ^ l7) * 8);
#pragma unroll
            for (int i = 0; i < 2; ++i)
                af[i] = *(const bf16x8*)(As + (wm * 64 + i * 32 + l31) * 64 + sg);
#pragma unroll
            for (int j = 0; j < 2; ++j)
                bfr[j] = *(const bf16x8*)(Bs + (wn * 64 + j * 32 + l31) * 64 + sg);
#pragma unroll
            for (int i = 0; i < 2; ++i)
#pragma unroll
                for (int j = 0; j < 2; ++j)
                    acc[i][j] = __builtin_amdgcn_mfma_f32_32x32x16_bf16(
                        af[i], bfr[j], acc[i][j], 0, 0, 0);
        }
        __syncthreads();
    }

    // Epilogue: 32x32 C/D layout (m74/m101): col = lane&31,
    // row = (reg&3) + 8*(reg>>2) + 4*(lane>>5), reg in [0,16)
    const int ccol  = lane & 31;
    const int rbase = (lane >> 5) * 4;
#pragma unroll
    for (int i = 0; i < 2; ++i) {
#pragma unroll
        for (int j = 0; j < 2; ++j) {
            float* Cp = C + (size_t)(m0 + wm * 64 + i * 32 + rbase) * J_DIM
                          + (j0 + wn * 64 + j * 32 + ccol);
#pragma unroll
            for (int q = 0; q < 4; ++q)
#pragma unroll
                for (int r = 0; r < 4; ++r)
                    Cp[(size_t)(q * 8 + r) * J_DIM] = acc[i][j][q * 4 + r];
        }
    }
}

extern "C" void kernel_launch(void* const* d_in, const int* in_sizes, int n_in,
                              void* d_out, int out_size, void* d_ws, size_t ws_size,
                              hipStream_t stream) {
    const float* A = (const float*)d_in[0];   // [8192,1024]
    const float* W = (const float*)d_in[1];   // [64,1024,32]
    float* out = (float*)d_out;               // [8192,64,32] == [8192,2048]

    unsigned short* Ab = (unsigned short*)d_ws;                 // 16 MB
    unsigned short* Bt = Ab + (size_t)M_DIM * N_IN;             // +4 MB

    convert_A<<<M_DIM * N_IN / (256 * 4), 256, 0, stream>>>(A, Ab);
    convert_W<<<dim3(N_IN / 64, E_DIM), 256, 0, stream>>>(W, Bt);
    gemm_bt<<<dim3(M_DIM / 128, J_DIM / 128), 256, 0, stream>>>(Ab, Bt, out);
}

// Round 4
// 127.578 us; speedup vs baseline: 1.1359x; 1.0623x over previous
//
#include <hip/hip_runtime.h>
#include <stdint.h>

// Problem: out[m,e,k] = sum_n A[m,n] * W[e,n,k]
// == GEMM C[8192,2048] = A[8192,1024] x B[1024,2048], B[n, e*32+k] = W[e,n,k]
// Output flat layout m*2048 + e*32 + k matches [M,E,K] exactly.
//
// Round-4 structure: A through LDS (global_load_lds + XOR swizzle, verified
// conflict-free in round 2); B fragments DIRECT from global (B is 4 MB,
// L2-resident, reused 32x per tile) in k-group-major layout BG[kgroup][j][8].
// Block 256x128, 4 waves 2x2, wave tile 128x64 = 8x4 of 16x16x32 MFMAs.
// FLOP per LDS byte: 64 (vs 32 in round 2) -> MFMA-dominant balance.

#define M_DIM 8192
#define N_IN  1024   // reduction dim
#define E_DIM 64
#define K_DIM 32
#define J_DIM 2048   // E*K output columns

typedef __attribute__((ext_vector_type(8))) __bf16 bf16x8;
typedef __attribute__((ext_vector_type(4))) float floatx4;

__device__ inline unsigned short f2bf(float f) {
    union { float f; unsigned u; } v; v.f = f;
    unsigned u = v.u;
    u += 0x7fff + ((u >> 16) & 1);   // round-to-nearest-even
    return (unsigned short)(u >> 16);
}

// A [8192,1024] f32 -> Ab bf16 (same row-major layout). 4 elements/thread.
__global__ __launch_bounds__(256) void convert_A(const float* __restrict__ A,
                                                 unsigned short* __restrict__ Ab) {
    size_t i = (size_t)blockIdx.x * 256 + threadIdx.x;
    const float4 v = ((const float4*)A)[i];
    ushort4 o;
    o.x = f2bf(v.x); o.y = f2bf(v.y); o.z = f2bf(v.z); o.w = f2bf(v.w);
    ((ushort4*)Ab)[i] = o;
}

// W [64][1024][32] f32 -> BG[kgroup=n>>3][j=e*32+k][t=n&7] bf16  (128 x 2048 x 8).
// B fragment for 16x16x32 MFMA: lane holds B^T[col j][k = kgroup*8 + t], t=0..7
// contiguous -> one 16B load per lane, lanes j-consecutive -> coalesced.
__global__ __launch_bounds__(256) void convert_W(const float* __restrict__ W,
                                                 unsigned short* __restrict__ BG) {
    const int t   = threadIdx.x;
    const int e   = blockIdx.y;        // 0..63
    const int n0  = blockIdx.x * 64;   // 16 slabs
    const int k   = t & 31;
    const int oct = t >> 5;            // 8 octets of n within the slab
    const float* Wp = W + ((size_t)e * N_IN + n0 + oct * 8) * K_DIM + k;
    unsigned short tmp[8];
#pragma unroll
    for (int u = 0; u < 8; ++u) tmp[u] = f2bf(Wp[(size_t)u * K_DIM]);  // coalesced per u
    unsigned short* out = BG + ((size_t)((n0 >> 3) + oct) * J_DIM + e * K_DIM + k) * 8;
    ushort4 lo, hi;
    lo.x = tmp[0]; lo.y = tmp[1]; lo.z = tmp[2]; lo.w = tmp[3];
    hi.x = tmp[4]; hi.y = tmp[5]; hi.z = tmp[6]; hi.w = tmp[7];
    ((ushort4*)out)[0] = lo;
    ((ushort4*)out)[1] = hi;           // 16B per thread, k-consecutive threads contiguous
}

__global__ __launch_bounds__(256, 2) void gemm_bt(const unsigned short* __restrict__ Ab,
                                                  const unsigned short* __restrict__ BG,
                                                  float* __restrict__ C) {
    __shared__ unsigned short As[256 * 64];   // 32 KB, [row][slot-group], XOR-swizzled

    const int tid  = threadIdx.x;
    const int wave = tid >> 6;
    const int lane = tid & 63;
    const int wm = wave >> 1, wn = wave & 1;
    const int m0 = blockIdx.x * 256;          // x = m-tile: consecutive blocks share B j-tile
    const int j0 = blockIdx.y * 128;

    floatx4 acc[8][4];
#pragma unroll
    for (int i = 0; i < 8; ++i)
#pragma unroll
        for (int j = 0; j < 4; ++j) acc[i][j] = (floatx4)(0.0f);

    // Staging: 32 chunks of 1KB (8 rows x 64 cols). Lane l covers LDS slot
    // (row_in_chunk = l>>3, group = l&7); fetches swizzled global group
    // (l&7)^(l>>3) so fragment reads (group g of row r at slot g^(r&7)) work.
    const int lrow8 = lane >> 3;
    const int gcol  = ((lane & 7) ^ lrow8) * 8;
    const int l15  = lane & 15;
    const int quad = lane >> 4;
    const int l7   = lane & 7;
    const int jcol = j0 + wn * 64 + l15;      // per-lane B column

    for (int kb = 0; kb < N_IN; kb += 64) {
#pragma unroll
        for (int l = 0; l < 8; ++l) {
            const int chunk = l * 4 + wave;          // 0..31
            const int row   = chunk * 8 + lrow8;     // 0..255
            const unsigned short* ga = Ab + (size_t)(m0 + row) * N_IN + kb + gcol;
            __builtin_amdgcn_global_load_lds(
                (const __attribute__((address_space(1))) unsigned int*)ga,
                (__attribute__((address_space(3))) unsigned int*)(As + chunk * 512),
                16, 0, 0);
        }
        // B fragments for both k-halves, direct from global (L2-hot).
        // Issued before the barrier: latency hides under the staging drain.
        bf16x8 bfr[2][4];
#pragma unroll
        for (int h = 0; h < 2; ++h) {
            const int kgroup = ((kb + h * 32) >> 3) + quad;
#pragma unroll
            for (int j = 0; j < 4; ++j)
                bfr[h][j] = *(const bf16x8*)(BG + ((size_t)kgroup * J_DIM + jcol + j * 16) * 8);
        }
        __syncthreads();

#pragma unroll
        for (int h = 0; h < 2; ++h) {
            const int sg = ((((h * 32) >> 3) + quad) ^ l7) * 8;
#pragma unroll
            for (int i = 0; i < 8; ++i) {
                const bf16x8 af = *(const bf16x8*)(As + (wm * 128 + i * 16 + l15) * 64 + sg);
#pragma unroll
                for (int j = 0; j < 4; ++j)
                    acc[i][j] = __builtin_amdgcn_mfma_f32_16x16x32_bf16(
                        af, bfr[h][j], acc[i][j], 0, 0, 0);
            }
        }
        __syncthreads();
    }

    // Epilogue: C/D layout col = lane&15, row = (lane>>4)*4 + reg
    const int crow = quad * 4;
    const int ccol = l15;
#pragma unroll
    for (int i = 0; i < 8; ++i) {
#pragma unroll
        for (int j = 0; j < 4; ++j) {
            float* Cp = C + (size_t)(m0 + wm * 128 + i * 16 + crow) * J_DIM
                          + (j0 + wn * 64 + j * 16 + ccol);
#pragma unroll
            for (int r = 0; r < 4; ++r)
                Cp[(size_t)r * J_DIM] = acc[i][j][r];
        }
    }
}

extern "C" void kernel_launch(void* const* d_in, const int* in_sizes, int n_in,
                              void* d_out, int out_size, void* d_ws, size_t ws_size,
                              hipStream_t stream) {
    const float* A = (const float*)d_in[0];   // [8192,1024]
    const float* W = (const float*)d_in[1];   // [64,1024,32]
    float* out = (float*)d_out;               // [8192,64,32] == [8192,2048]

    unsigned short* Ab = (unsigned short*)d_ws;                 // 16 MB
    unsigned short* BG = Ab + (size_t)M_DIM * N_IN;             // +4 MB

    convert_A<<<M_DIM * N_IN / (256 * 4), 256, 0, stream>>>(A, Ab);
    convert_W<<<dim3(N_IN / 64, E_DIM), 256, 0, stream>>>(W, BG);
    gemm_bt<<<dim3(M_DIM / 256, J_DIM / 128), 256, 0, stream>>>(Ab, BG, out);
}